// Round 21
// baseline (239.380 us; speedup 1.0000x reference)
//
#include <hip/hip_runtime.h>
#include <math.h>

#define N_NODES 100000
#define N_EDGES 1600000
#define E_TOT   1700000   // edges + self loops
#define NEG_SLOPE 0.2f
#define NBUCK 196         // ceil(100000/512) coarse buckets (dst>>9)
#define BCAP  12288       // per-bucket slab capacity (mean fill ~8704, sigma ~90)
#define G1_BLOCKS 1563    // ceil(100000/64)
#define SCAT2 1024        // scatter blocks, dispatched FIRST (overlap under gemm1 MFMA)
#define ECHUNK 1661       // ceil(1700000/1024)

typedef unsigned short ushort_t;
typedef unsigned int uint_t;
typedef __attribute__((ext_vector_type(8))) short bf16x8;
typedef __attribute__((ext_vector_type(4))) float f32x4;

__device__ __forceinline__ float lrelu(float v) { return v > 0.f ? v : NEG_SLOPE * v; }
__device__ __forceinline__ float bf16lo(uint_t u) { return __uint_as_float(u << 16); }
__device__ __forceinline__ float bf16hi(uint_t u) { return __uint_as_float(u & 0xffff0000u); }
// f32 -> bf16 round-to-nearest-even
__device__ __forceinline__ ushort_t f2bf(float f) {
    uint_t u = __float_as_uint(f);
    u += 0x7fffu + ((u >> 16) & 1u);
    return (ushort_t)(u >> 16);
}

union BU { uint4 u; bf16x8 b; };

// ---------------- prep: W1 -> bf16 B-fragment layout; zero bucket cursors ----------------
__global__ __launch_bounds__(256) void k_prep(const float* __restrict__ W1,
                                              ushort_t* __restrict__ Wb,
                                              int* __restrict__ bucket_cursor)
{
    const int idx = blockIdx.x * 256 + threadIdx.x;   // 16384 total
    if (blockIdx.x == 0 && threadIdx.x <= NBUCK) bucket_cursor[threadIdx.x] = 0;
    const int j  = idx & 7;
    const int kq = (idx >> 3) & 3;
    const int n  = (idx >> 5) & 15;
    const int tc = (idx >> 9) & 7;
    const int kc = idx >> 12;
    Wb[idx] = f2bf(W1[(kc * 32 + kq * 8 + j) * 128 + tc * 16 + n]);
}

// ---------------- fused scatter (blocks [0,SCAT2)) || MFMA-GEMM1 (+alpha1) ----------------
// Scatter blocks dispatched FIRST so their latency-bound work overlaps gemm1's MFMA.
// pairs entries packed: (src << 9) | (dst & 511)  — 26 bits used.
__global__ __launch_bounds__(256) void k_gemm1_scat(const float* __restrict__ x,
                                                    const ushort_t* __restrict__ Wb,
                                                    const float* __restrict__ a_src,
                                                    const float* __restrict__ a_dst,
                                                    ushort_t* __restrict__ hb,
                                                    float* __restrict__ as_,
                                                    float* __restrict__ ad_,
                                                    const int* __restrict__ ei,
                                                    int* __restrict__ bucket_cursor,
                                                    uint_t* __restrict__ pairs)
{
    __shared__ int lcnt[NBUCK];
    __shared__ int lbase[NBUCK];
    const int t = threadIdx.x;

    if (blockIdx.x < SCAT2) {
        const int estart = blockIdx.x * ECHUNK;
        const int eend = min(estart + ECHUNK, E_TOT);
        // pass 1: count
        for (int i = t; i < NBUCK; i += 256) lcnt[i] = 0;
        __syncthreads();
        for (int e = estart + t; e < eend; e += 256) {
            const int d = (e < N_EDGES) ? ei[N_EDGES + e] : (e - N_EDGES);
            atomicAdd(&lcnt[d >> 9], 1);
        }
        __syncthreads();
        // reserve contiguous chunks inside each bucket slab
        for (int i = t; i < NBUCK; i += 256) {
            const int c = lcnt[i];
            lbase[i] = (c > 0) ? atomicAdd(&bucket_cursor[i], c) : 0;
        }
        __syncthreads();
        for (int i = t; i < NBUCK; i += 256) lcnt[i] = 0;   // reuse as local cursor
        __syncthreads();
        // pass 2: re-read (L2-warm) and scatter packed entries into slabs
        for (int e = estart + t; e < eend; e += 256) {
            int s, d;
            if (e < N_EDGES) { s = ei[e]; d = ei[N_EDGES + e]; }
            else { s = d = e - N_EDGES; }
            const int b = d >> 9;
            const int pos = lbase[b] + atomicAdd(&lcnt[b], 1);
            pairs[(size_t)b * BCAP + pos] = ((uint_t)s << 9) | ((uint_t)d & 511u);
        }
        return;
    }

    // ---- gemm1 path (MFMA) ----
    const int blk = blockIdx.x - SCAT2;
    const int lane = t & 63;
    const int w = t >> 6;
    const int rbase = blk * 64 + w * 16;
    const int li = lane & 15;
    const int g = lane >> 4;

    f32x4 acc[8];
#pragma unroll
    for (int tc = 0; tc < 8; ++tc) acc[tc] = (f32x4){0.f, 0.f, 0.f, 0.f};

    int arow = rbase + li;
    if (arow > N_NODES - 1) arow = N_NODES - 1;
    const float* xr = x + (size_t)arow * 128 + g * 8;

#pragma unroll
    for (int kc = 0; kc < 4; ++kc) {
        const float4 a0 = *(const float4*)(xr + kc * 32);
        const float4 a1 = *(const float4*)(xr + kc * 32 + 4);
        BU au;
        au.u.x = (uint_t)f2bf(a0.x) | ((uint_t)f2bf(a0.y) << 16);
        au.u.y = (uint_t)f2bf(a0.z) | ((uint_t)f2bf(a0.w) << 16);
        au.u.z = (uint_t)f2bf(a1.x) | ((uint_t)f2bf(a1.y) << 16);
        au.u.w = (uint_t)f2bf(a1.z) | ((uint_t)f2bf(a1.w) << 16);
        const bf16x8 af = au.b;
#pragma unroll
        for (int tc = 0; tc < 8; ++tc) {
            const bf16x8 bf = *(const bf16x8*)(Wb + (size_t)(kc * 8 + tc) * 512 + li * 32 + g * 8);
            acc[tc] = __builtin_amdgcn_mfma_f32_16x16x32_bf16(af, bf, acc[tc], 0, 0, 0);
        }
    }

#pragma unroll
    for (int r = 0; r < 4; ++r) {
        const int row = rbase + g * 4 + r;
        if (row < N_NODES) {
            ushort_t* hp = hb + (size_t)row * 128 + li;
#pragma unroll
            for (int tc = 0; tc < 8; ++tc) hp[tc * 16] = f2bf(acc[tc][r]);
        }
    }

    float asv[8], adv[8];
#pragma unroll
    for (int tc = 0; tc < 8; ++tc) {
        asv[tc] = a_src[tc * 16 + li];
        adv[tc] = a_dst[tc * 16 + li];
    }
#pragma unroll
    for (int h = 0; h < 4; ++h) {
#pragma unroll
        for (int r = 0; r < 4; ++r) {
            float ps = acc[2 * h][r] * asv[2 * h] + acc[2 * h + 1][r] * asv[2 * h + 1];
            float pd = acc[2 * h][r] * adv[2 * h] + acc[2 * h + 1][r] * adv[2 * h + 1];
            ps += __shfl_xor(ps, 1); pd += __shfl_xor(pd, 1);
            ps += __shfl_xor(ps, 2); pd += __shfl_xor(pd, 2);
            ps += __shfl_xor(ps, 4); pd += __shfl_xor(pd, 4);
            ps += __shfl_xor(ps, 8); pd += __shfl_xor(pd, 8);
            const int row = rbase + g * 4 + r;
            if (li == 0 && row < N_NODES) {
                as_[row * 4 + h] = ps;
                ad_[row * 4 + h] = pd;
            }
        }
    }
}

// ---------------- buildC (1024 thr): self-scan of bucket counts + fine sort ----------------
__global__ __launch_bounds__(1024) void k_buildC(const uint_t* __restrict__ pairs,
                                                 const int* __restrict__ bucket_cursor,
                                                 int* __restrict__ row_ptr,
                                                 int* __restrict__ col_src)
{
    __shared__ int cnt[512];
    __shared__ int cur[512];
    __shared__ int sb[256];
    const int b = blockIdx.x, t = threadIdx.x;

    // inclusive scan of 196 bucket counts (threads 0..255 participate; all hit barriers)
    if (t < 256) sb[t] = (t < NBUCK) ? bucket_cursor[t] : 0;
    __syncthreads();
    for (int off = 1; off < 256; off <<= 1) {
        int a = 0;
        if (t < 256 && t >= off) a = sb[t - off];
        __syncthreads();
        if (t < 256 && t >= off) sb[t] += a;
        __syncthreads();
    }
    const int bcount = bucket_cursor[b];
    const int bprefix = sb[b] - bcount;   // global exclusive prefix for this bucket
    const int node0 = b << 9;
    const uint_t* bp = pairs + (size_t)b * BCAP;

    if (t < 512) cnt[t] = 0;
    __syncthreads();
    for (int e = t; e < bcount; e += 1024)
        atomicAdd(&cnt[bp[e] & 511u], 1);
    __syncthreads();

    int v = 0;
    if (t < 512) { v = cnt[t]; cur[t] = v; }
    __syncthreads();
    for (int off = 1; off < 512; off <<= 1) {
        int a = 0;
        if (t < 512 && t >= off) a = cur[t - off];
        __syncthreads();
        if (t < 512 && t >= off) cur[t] += a;
        __syncthreads();
    }
    if (t < 512) {
        const int excl = bprefix + cur[t] - v;   // exclusive base for bin t
        const int node = node0 + t;
        if (node < N_NODES) row_ptr[node] = excl;
        cur[t] = excl;
    }
    if (b == 0 && t == 0) row_ptr[N_NODES] = E_TOT;
    __syncthreads();

    for (int e = t; e < bcount; e += 1024) {
        const uint_t pr = bp[e];
        const int pos = atomicAdd(&cur[pr & 511u], 1);
        col_src[pos] = (int)(pr >> 9);
    }
}

// ---------------- agg1: single-pass softmax + bias + ELU -> x2[N,128] bf16 ----------------
// (proven 77 us form: all 64 lanes gather one h-row per iteration — coalesced 256 B;
//  simple loop — the compiler schedules this better than manual pipelining, R18 lesson)
__global__ __launch_bounds__(64) void k_agg1(const ushort_t* __restrict__ hb,
                                             const float* __restrict__ as_,
                                             const float* __restrict__ ad_,
                                             const int* __restrict__ row_ptr,
                                             const int* __restrict__ col_src,
                                             const float* __restrict__ bias,
                                             ushort_t* __restrict__ x2b)
{
    __shared__ float sEx[256];
    __shared__ int sSrc[64];
    const int n = blockIdx.x;
    const int lane = threadIdx.x;
    const int start = row_ptr[n], end = row_ptr[n + 1];
    const float4 adv = *(const float4*)(ad_ + (size_t)n * 4);

    const int hsel = lane >> 4;
    const int c0 = lane * 2;
    float2 acc = make_float2(0.f, 0.f);
    float4 ds = make_float4(0.f, 0.f, 0.f, 0.f);
    for (int base = start; base < end; base += 64) {
        const int e = base + lane;
        const int cnt = min(64, end - base);
        float4 ex = make_float4(0.f, 0.f, 0.f, 0.f);
        int s = 0;
        if (e < end) {
            s = col_src[e];
            const float4 av = *(const float4*)(as_ + (size_t)s * 4);
            ex.x = __expf(lrelu(av.x + adv.x));
            ex.y = __expf(lrelu(av.y + adv.y));
            ex.z = __expf(lrelu(av.z + adv.z));
            ex.w = __expf(lrelu(av.w + adv.w));
            ds.x += ex.x; ds.y += ex.y; ds.z += ex.z; ds.w += ex.w;
        }
        __syncthreads();
        *(float4*)(sEx + lane * 4) = ex;
        sSrc[lane] = s;
        __syncthreads();
        for (int i = 0; i < cnt; ++i) {
            const float w = sEx[i * 4 + hsel];
            const uint_t hv = *(const uint_t*)(hb + (size_t)sSrc[i] * 128 + c0);
            acc.x = fmaf(w, bf16lo(hv), acc.x);
            acc.y = fmaf(w, bf16hi(hv), acc.y);
        }
    }
#pragma unroll
    for (int off = 32; off > 0; off >>= 1) {
        ds.x += __shfl_xor(ds.x, off);
        ds.y += __shfl_xor(ds.y, off);
        ds.z += __shfl_xor(ds.z, off);
        ds.w += __shfl_xor(ds.w, off);
    }
    const float denom = hsel == 0 ? ds.x : hsel == 1 ? ds.y : hsel == 2 ? ds.z : ds.w;
    float o0 = acc.x / denom + bias[c0];
    float o1 = acc.y / denom + bias[c0 + 1];
    o0 = o0 > 0.f ? o0 : __expf(o0) - 1.f;   // ELU
    o1 = o1 > 0.f ? o1 : __expf(o1) - 1.f;
    const uint_t q0 = f2bf(o0), q1 = f2bf(o1);
    *(uint_t*)(x2b + (size_t)n * 128 + c0) = q0 | (q1 << 16);
}

// ---------------- GEMM2: 64 rows/block, W2 staged once; fused alpha2 ----------------
__global__ __launch_bounds__(256) void k_gemm2(const ushort_t* __restrict__ x2b,
                                               const float* __restrict__ W,
                                               const float* __restrict__ a_src,
                                               const float* __restrict__ a_dst,
                                               ushort_t* __restrict__ hb2,
                                               float* __restrict__ as_,
                                               float* __restrict__ ad_)
{
    __shared__ float sW[128 * 32];
    const int t = threadIdx.x;
    {
        const float4* W4 = (const float4*)W;
        float4* s4 = (float4*)sW;
#pragma unroll
        for (int i = 0; i < 4; ++i) s4[t + 256 * i] = W4[t + 256 * i];
    }
    __syncthreads();

    const int rr = t >> 5;
    const int c = t & 31;
    const float a_s = a_src[c], a_d = a_dst[c];

    for (int g = 0; g < 8; ++g) {
        const int row = blockIdx.x * 64 + g * 8 + rr;
        if (row >= N_NODES) continue;
        const ushort_t* xp = x2b + (size_t)row * 128;

        float acc = 0.f;
        for (int k = 0; k < 128; k += 4) {
            const uint2 u = *(const uint2*)(xp + k);
            acc = fmaf(bf16lo(u.x), sW[(k + 0) * 32 + c], acc);
            acc = fmaf(bf16hi(u.x), sW[(k + 1) * 32 + c], acc);
            acc = fmaf(bf16lo(u.y), sW[(k + 2) * 32 + c], acc);
            acc = fmaf(bf16hi(u.y), sW[(k + 3) * 32 + c], acc);
        }

        hb2[(size_t)row * 32 + c] = f2bf(acc);
        float ps = acc * a_s, pd = acc * a_d;
#pragma unroll
        for (int off = 16; off > 0; off >>= 1) {
            ps += __shfl_xor(ps, off);
            pd += __shfl_xor(pd, off);
        }
        if (c == 0) { as_[row] = ps; ad_[row] = pd; }
    }
}

// ---------------- agg2: 2 ch/lane, 4-way edge split -> out[N,32] ----------------
__global__ __launch_bounds__(64) void k_agg2(const ushort_t* __restrict__ hb2,
                                             const float* __restrict__ as_,
                                             const float* __restrict__ ad_,
                                             const int* __restrict__ row_ptr,
                                             const int* __restrict__ col_src,
                                             const float* __restrict__ bias,
                                             float* __restrict__ out)
{
    __shared__ float sEx[64];
    __shared__ int sSrc[64];
    const int n = blockIdx.x;
    const int lane = threadIdx.x;
    const int start = row_ptr[n], end = row_ptr[n + 1];
    const float adn = ad_[n];

    const int quarter = lane >> 4;
    const int cg = lane & 15;
    const int c2 = cg * 2;

    float2 acc = make_float2(0.f, 0.f);
    float dsum = 0.f;
    for (int base = start; base < end; base += 64) {
        const int e = base + lane;
        const int cnt = min(64, end - base);
        float ex = 0.f; int s = 0;
        if (e < end) {
            s = col_src[e];
            ex = __expf(lrelu(as_[s] + adn));
            dsum += ex;
        }
        __syncthreads();
        sEx[lane] = ex;
        sSrc[lane] = s;
        __syncthreads();
        for (int i = quarter; i < cnt; i += 4) {
            const float w = sEx[i];
            const uint_t hv = *(const uint_t*)(hb2 + (size_t)sSrc[i] * 32 + c2);
            acc.x = fmaf(w, bf16lo(hv), acc.x);
            acc.y = fmaf(w, bf16hi(hv), acc.y);
        }
    }
#pragma unroll
    for (int off = 32; off > 0; off >>= 1) dsum += __shfl_xor(dsum, off);
    acc.x += __shfl_xor(acc.x, 16);
    acc.y += __shfl_xor(acc.y, 16);
    acc.x += __shfl_xor(acc.x, 32);
    acc.y += __shfl_xor(acc.y, 32);
    if (quarter == 0) {
        float2 o = make_float2(acc.x / dsum + bias[c2], acc.y / dsum + bias[c2 + 1]);
        *(float2*)(out + (size_t)n * 32 + c2) = o;
    }
}

extern "C" void kernel_launch(void* const* d_in, const int* in_sizes, int n_in,
                              void* d_out, int out_size, void* d_ws, size_t ws_size,
                              hipStream_t stream)
{
    const float* x      = (const float*)d_in[0];
    const int*   ei     = (const int*)d_in[1];
    const float* W1     = (const float*)d_in[2];
    const float* a_src1 = (const float*)d_in[3];
    const float* a_dst1 = (const float*)d_in[4];
    const float* b1     = (const float*)d_in[5];
    const float* W2     = (const float*)d_in[6];
    const float* a_src2 = (const float*)d_in[7];
    const float* a_dst2 = (const float*)d_in[8];
    const float* b2     = (const float*)d_in[9];
    float* out = (float*)d_out;

    char* p = (char*)d_ws;
    auto alloc = [&](size_t bytes) { char* q = p; p += (bytes + 255) & ~(size_t)255; return q; };
    ushort_t* h1b = (ushort_t*)alloc((size_t)N_NODES * 128 * 2);
    ushort_t* x2b = (ushort_t*)alloc((size_t)N_NODES * 128 * 2);
    ushort_t* h2b = (ushort_t*)alloc((size_t)N_NODES * 32 * 2);
    ushort_t* Wb  = (ushort_t*)alloc((size_t)16384 * 2);
    float* as1    = (float*)alloc((size_t)N_NODES * 4 * 4);
    float* ad1    = (float*)alloc((size_t)N_NODES * 4 * 4);
    float* as2    = (float*)alloc((size_t)N_NODES * 4);
    float* ad2    = (float*)alloc((size_t)N_NODES * 4);
    int* row_ptr  = (int*)alloc((size_t)(N_NODES + 1) * 4);
    int* bucket_cursor = (int*)alloc((NBUCK + 1) * 4);
    uint_t* pairs = (uint_t*)alloc((size_t)NBUCK * BCAP * 4);
    int* col_src  = (int*)alloc((size_t)E_TOT * 4);

    k_prep<<<64, 256, 0, stream>>>(W1, Wb, bucket_cursor);
    k_gemm1_scat<<<SCAT2 + G1_BLOCKS, 256, 0, stream>>>(
        x, Wb, a_src1, a_dst1, h1b, as1, ad1, ei, bucket_cursor, pairs);
    k_buildC<<<NBUCK, 1024, 0, stream>>>(pairs, bucket_cursor, row_ptr, col_src);
    k_agg1<<<N_NODES, 64, 0, stream>>>(h1b, as1, ad1, row_ptr, col_src, b1, x2b);
    k_gemm2<<<(N_NODES + 63) / 64, 256, 0, stream>>>(x2b, W2, a_src2, a_dst2, h2b, as2, ad2);
    k_agg2<<<N_NODES, 64, 0, stream>>>(h2b, as2, ad2, row_ptr, col_src, b2, out);
}

// Round 22
// 228.119 us; speedup vs baseline: 1.0494x; 1.0494x over previous
//
#include <hip/hip_runtime.h>
#include <math.h>

#define N_NODES 100000
#define N_EDGES 1600000
#define E_TOT   1700000   // edges + self loops
#define NEG_SLOPE 0.2f
#define NBUCK 196         // ceil(100000/512) coarse buckets (dst>>9)
#define BCAP  12288       // per-bucket slab capacity (mean fill ~8704, sigma ~90)
#define G1_BLOCKS 1563    // ceil(100000/64)
#define SCAT2 512         // scatter blocks, dispatched FIRST (overlap under gemm1 MFMA)
#define ECHUNK 3321       // ceil(1700000/512)

typedef unsigned short ushort_t;
typedef unsigned int uint_t;
typedef __attribute__((ext_vector_type(8))) short bf16x8;
typedef __attribute__((ext_vector_type(4))) float f32x4;

__device__ __forceinline__ float lrelu(float v) { return v > 0.f ? v : NEG_SLOPE * v; }
__device__ __forceinline__ float bf16lo(uint_t u) { return __uint_as_float(u << 16); }
__device__ __forceinline__ float bf16hi(uint_t u) { return __uint_as_float(u & 0xffff0000u); }
// f32 -> bf16 round-to-nearest-even
__device__ __forceinline__ ushort_t f2bf(float f) {
    uint_t u = __float_as_uint(f);
    u += 0x7fffu + ((u >> 16) & 1u);
    return (ushort_t)(u >> 16);
}

union BU { uint4 u; bf16x8 b; };

// ---------------- prep: W1 -> bf16 B-fragment layout; zero bucket cursors ----------------
__global__ __launch_bounds__(256) void k_prep(const float* __restrict__ W1,
                                              ushort_t* __restrict__ Wb,
                                              int* __restrict__ bucket_cursor)
{
    const int idx = blockIdx.x * 256 + threadIdx.x;   // 16384 total
    if (blockIdx.x == 0 && threadIdx.x <= NBUCK) bucket_cursor[threadIdx.x] = 0;
    const int j  = idx & 7;
    const int kq = (idx >> 3) & 3;
    const int n  = (idx >> 5) & 15;
    const int tc = (idx >> 9) & 7;
    const int kc = idx >> 12;
    Wb[idx] = f2bf(W1[(kc * 32 + kq * 8 + j) * 128 + tc * 16 + n]);
}

// ---------------- fused scatter (blocks [0,SCAT2)) || MFMA-GEMM1 (+alpha1) ----------------
// pairs entries packed: (src << 9) | (dst & 511)  — 26 bits used.
__global__ __launch_bounds__(256) void k_gemm1_scat(const float* __restrict__ x,
                                                    const ushort_t* __restrict__ Wb,
                                                    const float* __restrict__ a_src,
                                                    const float* __restrict__ a_dst,
                                                    ushort_t* __restrict__ hb,
                                                    float* __restrict__ as_,
                                                    float* __restrict__ ad_,
                                                    const int* __restrict__ ei,
                                                    int* __restrict__ bucket_cursor,
                                                    uint_t* __restrict__ pairs)
{
    __shared__ int lcnt[NBUCK];
    __shared__ int lbase[NBUCK];
    const int t = threadIdx.x;

    if (blockIdx.x < SCAT2) {
        const int estart = blockIdx.x * ECHUNK;
        const int eend = min(estart + ECHUNK, E_TOT);
        // pass 1: count
        for (int i = t; i < NBUCK; i += 256) lcnt[i] = 0;
        __syncthreads();
        for (int e = estart + t; e < eend; e += 256) {
            const int d = (e < N_EDGES) ? ei[N_EDGES + e] : (e - N_EDGES);
            atomicAdd(&lcnt[d >> 9], 1);
        }
        __syncthreads();
        // reserve contiguous chunks inside each bucket slab
        for (int i = t; i < NBUCK; i += 256) {
            const int c = lcnt[i];
            lbase[i] = (c > 0) ? atomicAdd(&bucket_cursor[i], c) : 0;
        }
        __syncthreads();
        for (int i = t; i < NBUCK; i += 256) lcnt[i] = 0;   // reuse as local cursor
        __syncthreads();
        // pass 2: re-read (L2-warm) and scatter packed entries into slabs
        for (int e = estart + t; e < eend; e += 256) {
            int s, d;
            if (e < N_EDGES) { s = ei[e]; d = ei[N_EDGES + e]; }
            else { s = d = e - N_EDGES; }
            const int b = d >> 9;
            const int pos = lbase[b] + atomicAdd(&lcnt[b], 1);
            pairs[(size_t)b * BCAP + pos] = ((uint_t)s << 9) | ((uint_t)d & 511u);
        }
        return;
    }

    // ---- gemm1 path (MFMA) ----
    const int blk = blockIdx.x - SCAT2;
    const int lane = t & 63;
    const int w = t >> 6;
    const int rbase = blk * 64 + w * 16;
    const int li = lane & 15;
    const int g = lane >> 4;

    f32x4 acc[8];
#pragma unroll
    for (int tc = 0; tc < 8; ++tc) acc[tc] = (f32x4){0.f, 0.f, 0.f, 0.f};

    int arow = rbase + li;
    if (arow > N_NODES - 1) arow = N_NODES - 1;
    const float* xr = x + (size_t)arow * 128 + g * 8;

#pragma unroll
    for (int kc = 0; kc < 4; ++kc) {
        const float4 a0 = *(const float4*)(xr + kc * 32);
        const float4 a1 = *(const float4*)(xr + kc * 32 + 4);
        BU au;
        au.u.x = (uint_t)f2bf(a0.x) | ((uint_t)f2bf(a0.y) << 16);
        au.u.y = (uint_t)f2bf(a0.z) | ((uint_t)f2bf(a0.w) << 16);
        au.u.z = (uint_t)f2bf(a1.x) | ((uint_t)f2bf(a1.y) << 16);
        au.u.w = (uint_t)f2bf(a1.z) | ((uint_t)f2bf(a1.w) << 16);
        const bf16x8 af = au.b;
#pragma unroll
        for (int tc = 0; tc < 8; ++tc) {
            const bf16x8 bf = *(const bf16x8*)(Wb + (size_t)(kc * 8 + tc) * 512 + li * 32 + g * 8);
            acc[tc] = __builtin_amdgcn_mfma_f32_16x16x32_bf16(af, bf, acc[tc], 0, 0, 0);
        }
    }

#pragma unroll
    for (int r = 0; r < 4; ++r) {
        const int row = rbase + g * 4 + r;
        if (row < N_NODES) {
            ushort_t* hp = hb + (size_t)row * 128 + li;
#pragma unroll
            for (int tc = 0; tc < 8; ++tc) hp[tc * 16] = f2bf(acc[tc][r]);
        }
    }

    float asv[8], adv[8];
#pragma unroll
    for (int tc = 0; tc < 8; ++tc) {
        asv[tc] = a_src[tc * 16 + li];
        adv[tc] = a_dst[tc * 16 + li];
    }
#pragma unroll
    for (int h = 0; h < 4; ++h) {
#pragma unroll
        for (int r = 0; r < 4; ++r) {
            float ps = acc[2 * h][r] * asv[2 * h] + acc[2 * h + 1][r] * asv[2 * h + 1];
            float pd = acc[2 * h][r] * adv[2 * h] + acc[2 * h + 1][r] * adv[2 * h + 1];
            ps += __shfl_xor(ps, 1); pd += __shfl_xor(pd, 1);
            ps += __shfl_xor(ps, 2); pd += __shfl_xor(pd, 2);
            ps += __shfl_xor(ps, 4); pd += __shfl_xor(pd, 4);
            ps += __shfl_xor(ps, 8); pd += __shfl_xor(pd, 8);
            const int row = rbase + g * 4 + r;
            if (li == 0 && row < N_NODES) {
                as_[row * 4 + h] = ps;
                ad_[row * 4 + h] = pd;
            }
        }
    }
}

// ---------------- buildC (1024 thr): self-scan of bucket counts + fine sort ----------------
__global__ __launch_bounds__(1024) void k_buildC(const uint_t* __restrict__ pairs,
                                                 const int* __restrict__ bucket_cursor,
                                                 int* __restrict__ row_ptr,
                                                 int* __restrict__ col_src)
{
    __shared__ int cnt[512];
    __shared__ int cur[512];
    __shared__ int sb[256];
    const int b = blockIdx.x, t = threadIdx.x;

    // inclusive scan of 196 bucket counts (threads 0..255 participate; all hit barriers)
    if (t < 256) sb[t] = (t < NBUCK) ? bucket_cursor[t] : 0;
    __syncthreads();
    for (int off = 1; off < 256; off <<= 1) {
        int a = 0;
        if (t < 256 && t >= off) a = sb[t - off];
        __syncthreads();
        if (t < 256 && t >= off) sb[t] += a;
        __syncthreads();
    }
    const int bcount = bucket_cursor[b];
    const int bprefix = sb[b] - bcount;   // global exclusive prefix for this bucket
    const int node0 = b << 9;
    const uint_t* bp = pairs + (size_t)b * BCAP;

    if (t < 512) cnt[t] = 0;
    __syncthreads();
    for (int e = t; e < bcount; e += 1024)
        atomicAdd(&cnt[bp[e] & 511u], 1);
    __syncthreads();

    int v = 0;
    if (t < 512) { v = cnt[t]; cur[t] = v; }
    __syncthreads();
    for (int off = 1; off < 512; off <<= 1) {
        int a = 0;
        if (t < 512 && t >= off) a = cur[t - off];
        __syncthreads();
        if (t < 512 && t >= off) cur[t] += a;
        __syncthreads();
    }
    if (t < 512) {
        const int excl = bprefix + cur[t] - v;   // exclusive base for bin t
        const int node = node0 + t;
        if (node < N_NODES) row_ptr[node] = excl;
        cur[t] = excl;
    }
    if (b == 0 && t == 0) row_ptr[N_NODES] = E_TOT;
    __syncthreads();

    for (int e = t; e < bcount; e += 1024) {
        const uint_t pr = bp[e];
        const int pos = atomicAdd(&cur[pr & 511u], 1);
        col_src[pos] = (int)(pr >> 9);
    }
}

// ---------------- agg1: single-pass softmax + bias + ELU -> x2[N,128] bf16 ----------------
// (proven 77 us form: all 64 lanes gather one h-row per iteration — coalesced 256 B)
__global__ __launch_bounds__(64) void k_agg1(const ushort_t* __restrict__ hb,
                                             const float* __restrict__ as_,
                                             const float* __restrict__ ad_,
                                             const int* __restrict__ row_ptr,
                                             const int* __restrict__ col_src,
                                             const float* __restrict__ bias,
                                             ushort_t* __restrict__ x2b)
{
    __shared__ float sEx[256];
    __shared__ int sSrc[64];
    const int n = blockIdx.x;
    const int lane = threadIdx.x;
    const int start = row_ptr[n], end = row_ptr[n + 1];
    const float4 adv = *(const float4*)(ad_ + (size_t)n * 4);

    const int hsel = lane >> 4;
    const int c0 = lane * 2;
    float2 acc = make_float2(0.f, 0.f);
    float4 ds = make_float4(0.f, 0.f, 0.f, 0.f);
    for (int base = start; base < end; base += 64) {
        const int e = base + lane;
        const int cnt = min(64, end - base);
        float4 ex = make_float4(0.f, 0.f, 0.f, 0.f);
        int s = 0;
        if (e < end) {
            s = col_src[e];
            const float4 av = *(const float4*)(as_ + (size_t)s * 4);
            ex.x = __expf(lrelu(av.x + adv.x));
            ex.y = __expf(lrelu(av.y + adv.y));
            ex.z = __expf(lrelu(av.z + adv.z));
            ex.w = __expf(lrelu(av.w + adv.w));
            ds.x += ex.x; ds.y += ex.y; ds.z += ex.z; ds.w += ex.w;
        }
        __syncthreads();
        *(float4*)(sEx + lane * 4) = ex;
        sSrc[lane] = s;
        __syncthreads();
        for (int i = 0; i < cnt; ++i) {
            const float w = sEx[i * 4 + hsel];
            const uint_t hv = *(const uint_t*)(hb + (size_t)sSrc[i] * 128 + c0);
            acc.x = fmaf(w, bf16lo(hv), acc.x);
            acc.y = fmaf(w, bf16hi(hv), acc.y);
        }
    }
#pragma unroll
    for (int off = 32; off > 0; off >>= 1) {
        ds.x += __shfl_xor(ds.x, off);
        ds.y += __shfl_xor(ds.y, off);
        ds.z += __shfl_xor(ds.z, off);
        ds.w += __shfl_xor(ds.w, off);
    }
    const float denom = hsel == 0 ? ds.x : hsel == 1 ? ds.y : hsel == 2 ? ds.z : ds.w;
    float o0 = acc.x / denom + bias[c0];
    float o1 = acc.y / denom + bias[c0 + 1];
    o0 = o0 > 0.f ? o0 : __expf(o0) - 1.f;   // ELU
    o1 = o1 > 0.f ? o1 : __expf(o1) - 1.f;
    const uint_t q0 = f2bf(o0), q1 = f2bf(o1);
    *(uint_t*)(x2b + (size_t)n * 128 + c0) = q0 | (q1 << 16);
}

// ---------------- GEMM2: 64 rows/block, W2 staged once; fused alpha2 ----------------
__global__ __launch_bounds__(256) void k_gemm2(const ushort_t* __restrict__ x2b,
                                               const float* __restrict__ W,
                                               const float* __restrict__ a_src,
                                               const float* __restrict__ a_dst,
                                               ushort_t* __restrict__ hb2,
                                               float* __restrict__ as_,
                                               float* __restrict__ ad_)
{
    __shared__ float sW[128 * 32];
    const int t = threadIdx.x;
    {
        const float4* W4 = (const float4*)W;
        float4* s4 = (float4*)sW;
#pragma unroll
        for (int i = 0; i < 4; ++i) s4[t + 256 * i] = W4[t + 256 * i];
    }
    __syncthreads();

    const int rr = t >> 5;
    const int c = t & 31;
    const float a_s = a_src[c], a_d = a_dst[c];

    for (int g = 0; g < 8; ++g) {
        const int row = blockIdx.x * 64 + g * 8 + rr;
        if (row >= N_NODES) continue;
        const ushort_t* xp = x2b + (size_t)row * 128;

        float acc = 0.f;
        for (int k = 0; k < 128; k += 4) {
            const uint2 u = *(const uint2*)(xp + k);
            acc = fmaf(bf16lo(u.x), sW[(k + 0) * 32 + c], acc);
            acc = fmaf(bf16hi(u.x), sW[(k + 1) * 32 + c], acc);
            acc = fmaf(bf16lo(u.y), sW[(k + 2) * 32 + c], acc);
            acc = fmaf(bf16hi(u.y), sW[(k + 3) * 32 + c], acc);
        }

        hb2[(size_t)row * 32 + c] = f2bf(acc);
        float ps = acc * a_s, pd = acc * a_d;
#pragma unroll
        for (int off = 16; off > 0; off >>= 1) {
            ps += __shfl_xor(ps, off);
            pd += __shfl_xor(pd, off);
        }
        if (c == 0) { as_[row] = ps; ad_[row] = pd; }
    }
}

// ---------------- agg2: 2 ch/lane, 4-way edge split -> out[N,32] ----------------
__global__ __launch_bounds__(64) void k_agg2(const ushort_t* __restrict__ hb2,
                                             const float* __restrict__ as_,
                                             const float* __restrict__ ad_,
                                             const int* __restrict__ row_ptr,
                                             const int* __restrict__ col_src,
                                             const float* __restrict__ bias,
                                             float* __restrict__ out)
{
    __shared__ float sEx[64];
    __shared__ int sSrc[64];
    const int n = blockIdx.x;
    const int lane = threadIdx.x;
    const int start = row_ptr[n], end = row_ptr[n + 1];
    const float adn = ad_[n];

    const int quarter = lane >> 4;
    const int cg = lane & 15;
    const int c2 = cg * 2;

    float2 acc = make_float2(0.f, 0.f);
    float dsum = 0.f;
    for (int base = start; base < end; base += 64) {
        const int e = base + lane;
        const int cnt = min(64, end - base);
        float ex = 0.f; int s = 0;
        if (e < end) {
            s = col_src[e];
            ex = __expf(lrelu(as_[s] + adn));
            dsum += ex;
        }
        __syncthreads();
        sEx[lane] = ex;
        sSrc[lane] = s;
        __syncthreads();
        for (int i = quarter; i < cnt; i += 4) {
            const float w = sEx[i];
            const uint_t hv = *(const uint_t*)(hb2 + (size_t)sSrc[i] * 32 + c2);
            acc.x = fmaf(w, bf16lo(hv), acc.x);
            acc.y = fmaf(w, bf16hi(hv), acc.y);
        }
    }
#pragma unroll
    for (int off = 32; off > 0; off >>= 1) dsum += __shfl_xor(dsum, off);
    acc.x += __shfl_xor(acc.x, 16);
    acc.y += __shfl_xor(acc.y, 16);
    acc.x += __shfl_xor(acc.x, 32);
    acc.y += __shfl_xor(acc.y, 32);
    if (quarter == 0) {
        float2 o = make_float2(acc.x / dsum + bias[c2], acc.y / dsum + bias[c2 + 1]);
        *(float2*)(out + (size_t)n * 32 + c2) = o;
    }
}

extern "C" void kernel_launch(void* const* d_in, const int* in_sizes, int n_in,
                              void* d_out, int out_size, void* d_ws, size_t ws_size,
                              hipStream_t stream)
{
    const float* x      = (const float*)d_in[0];
    const int*   ei     = (const int*)d_in[1];
    const float* W1     = (const float*)d_in[2];
    const float* a_src1 = (const float*)d_in[3];
    const float* a_dst1 = (const float*)d_in[4];
    const float* b1     = (const float*)d_in[5];
    const float* W2     = (const float*)d_in[6];
    const float* a_src2 = (const float*)d_in[7];
    const float* a_dst2 = (const float*)d_in[8];
    const float* b2     = (const float*)d_in[9];
    float* out = (float*)d_out;

    char* p = (char*)d_ws;
    auto alloc = [&](size_t bytes) { char* q = p; p += (bytes + 255) & ~(size_t)255; return q; };
    ushort_t* h1b = (ushort_t*)alloc((size_t)N_NODES * 128 * 2);
    ushort_t* x2b = (ushort_t*)alloc((size_t)N_NODES * 128 * 2);
    ushort_t* h2b = (ushort_t*)alloc((size_t)N_NODES * 32 * 2);
    ushort_t* Wb  = (ushort_t*)alloc((size_t)16384 * 2);
    float* as1    = (float*)alloc((size_t)N_NODES * 4 * 4);
    float* ad1    = (float*)alloc((size_t)N_NODES * 4 * 4);
    float* as2    = (float*)alloc((size_t)N_NODES * 4);
    float* ad2    = (float*)alloc((size_t)N_NODES * 4);
    int* row_ptr  = (int*)alloc((size_t)(N_NODES + 1) * 4);
    int* bucket_cursor = (int*)alloc((NBUCK + 1) * 4);
    uint_t* pairs = (uint_t*)alloc((size_t)NBUCK * BCAP * 4);
    int* col_src  = (int*)alloc((size_t)E_TOT * 4);

    k_prep<<<64, 256, 0, stream>>>(W1, Wb, bucket_cursor);
    k_gemm1_scat<<<SCAT2 + G1_BLOCKS, 256, 0, stream>>>(
        x, Wb, a_src1, a_dst1, h1b, as1, ad1, ei, bucket_cursor, pairs);
    k_buildC<<<NBUCK, 1024, 0, stream>>>(pairs, bucket_cursor, row_ptr, col_src);
    k_agg1<<<N_NODES, 64, 0, stream>>>(h1b, as1, ad1, row_ptr, col_src, b1, x2b);
    k_gemm2<<<(N_NODES + 63) / 64, 256, 0, stream>>>(x2b, W2, a_src2, a_dst2, h2b, as2, ad2);
    k_agg2<<<N_NODES, 64, 0, stream>>>(h2b, as2, ad2, row_ptr, col_src, b2, out);
}